// Round 10
// baseline (252.717 us; speedup 1.0000x reference)
//
#include <hip/hip_runtime.h>
#include <hip/hip_bf16.h>
#include <cstdint>
#include <cstddef>

typedef unsigned short u16;
typedef __attribute__((ext_vector_type(8))) short bf16x8;
typedef __attribute__((ext_vector_type(4))) short bf16x4;
typedef __attribute__((ext_vector_type(4))) float f32x4;

#define AS1 __attribute__((address_space(1)))
#define AS3 __attribute__((address_space(3)))

// round-to-nearest-even f32 -> bf16 bits
static __device__ __forceinline__ u16 f2bf(float f) {
  union { float f; unsigned u; } c;
  c.f = f;
  unsigned r = c.u + 0x7fffu + ((c.u >> 16) & 1u);
  return (u16)(r >> 16);
}

// ---------------- prep kernels ----------------

__global__ __launch_bounds__(256) void cast_x_kernel(const float* __restrict__ in,
                                                     u16* __restrict__ out, int n4) {
  int i = blockIdx.x * blockDim.x + threadIdx.x;
  if (i < n4) {
    float4 v = reinterpret_cast<const float4*>(in)[i];
    ushort4 o;
    o.x = f2bf(v.x); o.y = f2bf(v.y); o.z = f2bf(v.z); o.w = f2bf(v.w);
    reinterpret_cast<ushort4*>(out)[i] = o;
  }
}

// out[C][R] (bf16) = transpose of in[R][C] (f32)
__global__ __launch_bounds__(256) void transpose_cast_kernel(const float* __restrict__ in,
                                                             u16* __restrict__ out,
                                                             int R, int C) {
  __shared__ float tile[32][33];
  int bx = blockIdx.x, by = blockIdx.y;
  int tx = threadIdx.x, ty = threadIdx.y;
  #pragma unroll
  for (int i = ty; i < 32; i += 8)
    tile[i][tx] = in[(size_t)(by * 32 + i) * C + bx * 32 + tx];
  __syncthreads();
  #pragma unroll
  for (int i = ty; i < 32; i += 8)
    out[(size_t)(bx * 32 + i) * R + by * 32 + tx] = f2bf(tile[tx][i]);
}

// V [BH][2048][64] bf16 -> Vt [BH][64][2048] bf16. grid (32 t-tiles, 32 bh), block (64,8)
__global__ __launch_bounds__(512) void transpose_v_kernel(const u16* __restrict__ in,
                                                          u16* __restrict__ out) {
  __shared__ u16 tile[64][65];
  const int bh = blockIdx.y;
  const int t0 = blockIdx.x * 64;
  const int tx = threadIdx.x, ty = threadIdx.y;
  const u16* src = in + (size_t)bh * 2048 * 64;
  u16* dst = out + (size_t)bh * 64 * 2048;
  #pragma unroll
  for (int i = ty; i < 64; i += 8)
    tile[i][tx] = src[(size_t)(t0 + i) * 64 + tx];     // tile[t][d]
  __syncthreads();
  #pragma unroll
  for (int i = ty; i < 64; i += 8)
    dst[(size_t)i * 2048 + t0 + tx] = tile[tx][i];
}

// ---------------- GEMM mainloop (m97 structure: 128x128 tile, BK=64) ----------------
static __device__ __forceinline__ void gemm_mainloop(
    const u16* __restrict__ A, const u16* __restrict__ Bt, int K,
    int brow, int bcol, u16* lsA, u16* lsB, f32x4 acc[4][4]) {
  const int tid  = threadIdx.x;
  const int lane = tid & 63;
  const int wave = tid >> 6;
  const int wr = wave >> 1, wc = wave & 1;
  const int r = lane & 15, g = lane >> 4;

  for (int k0 = 0; k0 < K; k0 += 64) {
    #pragma unroll
    for (int i = 0; i < 4; ++i) {
      int chunk = i * 4 + wave;          // 16 chunks x 1KB per tile
      int e = (chunk * 64 + lane) * 8;   // element index in tile
      int rr = e >> 6, cc = e & 63;
      __builtin_amdgcn_global_load_lds(
          (const AS1 void*)(A + (size_t)(brow + rr) * K + k0 + cc),
          (AS3 void*)(lsA + chunk * 512), 16, 0, 0);
      __builtin_amdgcn_global_load_lds(
          (const AS1 void*)(Bt + (size_t)(bcol + rr) * K + k0 + cc),
          (AS3 void*)(lsB + chunk * 512), 16, 0, 0);
    }
    __syncthreads();
    #pragma unroll
    for (int kk = 0; kk < 64; kk += 32) {
      bf16x8 af[4], bfr[4];
      #pragma unroll
      for (int m = 0; m < 4; ++m)
        af[m] = *reinterpret_cast<const bf16x8*>(lsA + (wr * 64 + m * 16 + r) * 64 + kk + g * 8);
      #pragma unroll
      for (int n = 0; n < 4; ++n)
        bfr[n] = *reinterpret_cast<const bf16x8*>(lsB + (wc * 64 + n * 16 + r) * 64 + kk + g * 8);
      #pragma unroll
      for (int m = 0; m < 4; ++m)
        #pragma unroll
        for (int n = 0; n < 4; ++n)
          acc[m][n] = __builtin_amdgcn_mfma_f32_16x16x32_bf16(af[m], bfr[n], acc[m][n], 0, 0, 0);
    }
    __syncthreads();
  }
}

// QKV projection; scatter Q/K/V -> [B*H][T][64] (V transposed later).
// Q gets 1/sqrt(64)*log2(e) folded (attention works in exp2 domain).
// XCD-aware block swizzle (768 blocks, 768%8==0 -> bijective).
__global__ __launch_bounds__(256) void gemm_qkv_kernel(
    const u16* __restrict__ A, const u16* __restrict__ Bt,
    const float* __restrict__ bias,
    u16* __restrict__ Qo, u16* __restrict__ Ko, u16* __restrict__ Vo) {
  __shared__ u16 lsA[128 * 64];
  __shared__ u16 lsB[128 * 64];
  f32x4 acc[4][4];
  #pragma unroll
  for (int m = 0; m < 4; ++m)
    #pragma unroll
    for (int n = 0; n < 4; ++n)
      acc[m][n] = (f32x4){0.f, 0.f, 0.f, 0.f};

  const int lin = blockIdx.y * 24 + blockIdx.x;   // dispatch order
  const int nl  = (lin & 7) * 96 + (lin >> 3);    // XCD swizzle
  const int brow = (nl / 24) * 128;
  const int bcol = (nl % 24) * 128;
  gemm_mainloop(A, Bt, 1024, brow, bcol, lsA, lsB, acc);

  const float QSC = 0.125f * 1.44269504088896f;
  const int lane = threadIdx.x & 63;
  const int wave = threadIdx.x >> 6;
  const int wr = wave >> 1, wc = wave & 1;
  const int r = lane & 15, g = lane >> 4;
  #pragma unroll
  for (int n = 0; n < 4; ++n) {
    int col = bcol + wc * 64 + n * 16 + r;         // in [0,3072)
    int s = col >> 10, h = (col >> 6) & 15, d = col & 63;
    float bv = bias[col];
    u16* dst = (s == 0) ? Qo : (s == 1) ? Ko : Vo;
    float sc = (s == 0) ? QSC : 1.f;
    #pragma unroll
    for (int m = 0; m < 4; ++m) {
      #pragma unroll
      for (int j = 0; j < 4; ++j) {
        int rowj = brow + wr * 64 + m * 16 + g * 4 + j;   // b*2048 + t
        int b = rowj >> 11, t = rowj & 2047;
        dst[((size_t)(b * 16 + h) * 2048 + t) * 64 + d] = f2bf((acc[m][n][j] + bv) * sc);
      }
    }
  }
}

// Output projection: out[4096][1024] f32 = attn @ Wout + b_out
// 128x64 tiles -> 512 blocks (2/CU, was 1/CU at 128x128). 4 waves stacked on M.
__global__ __launch_bounds__(256) void gemm_out_kernel(
    const u16* __restrict__ A, const u16* __restrict__ Bt,
    const float* __restrict__ bias, float* __restrict__ out) {
  __shared__ u16 lsA[128 * 64];   // 16KB
  __shared__ u16 lsB[64 * 64];    // 8KB
  f32x4 acc[2][4];
  #pragma unroll
  for (int m = 0; m < 2; ++m)
    #pragma unroll
    for (int n = 0; n < 4; ++n)
      acc[m][n] = (f32x4){0.f, 0.f, 0.f, 0.f};

  const int lin = blockIdx.y * 16 + blockIdx.x;
  const int nl  = (lin & 7) * 64 + (lin >> 3);    // 512 blocks, bijective
  const int brow = (nl / 16) * 128;
  const int bcol = (nl % 16) * 64;

  const int tid  = threadIdx.x;
  const int lane = tid & 63;
  const int wave = tid >> 6;
  const int r = lane & 15, g = lane >> 4;

  for (int k0 = 0; k0 < 1024; k0 += 64) {
    // stage: 16 A-chunks + 8 B-chunks of 1KB, 6 per wave (wave-uniform branch)
    #pragma unroll
    for (int i = 0; i < 6; ++i) {
      int chunk = wave * 6 + i;
      if (chunk < 16) {
        int e = (chunk * 64 + lane) * 8;
        int rr = e >> 6, cc = e & 63;
        __builtin_amdgcn_global_load_lds(
            (const AS1 void*)(A + (size_t)(brow + rr) * 1024 + k0 + cc),
            (AS3 void*)(lsA + chunk * 512), 16, 0, 0);
      } else {
        int ch = chunk - 16;
        int e = (ch * 64 + lane) * 8;
        int rr = e >> 6, cc = e & 63;
        __builtin_amdgcn_global_load_lds(
            (const AS1 void*)(Bt + (size_t)(bcol + rr) * 1024 + k0 + cc),
            (AS3 void*)(lsB + ch * 512), 16, 0, 0);
      }
    }
    __syncthreads();
    #pragma unroll
    for (int kk = 0; kk < 64; kk += 32) {
      bf16x8 af[2], bfr[4];
      #pragma unroll
      for (int m = 0; m < 2; ++m)
        af[m] = *reinterpret_cast<const bf16x8*>(lsA + (wave * 32 + m * 16 + r) * 64 + kk + g * 8);
      #pragma unroll
      for (int n = 0; n < 4; ++n)
        bfr[n] = *reinterpret_cast<const bf16x8*>(lsB + (n * 16 + r) * 64 + kk + g * 8);
      #pragma unroll
      for (int m = 0; m < 2; ++m)
        #pragma unroll
        for (int n = 0; n < 4; ++n)
          acc[m][n] = __builtin_amdgcn_mfma_f32_16x16x32_bf16(af[m], bfr[n], acc[m][n], 0, 0, 0);
    }
    __syncthreads();
  }

  #pragma unroll
  for (int n = 0; n < 4; ++n) {
    int col = bcol + n * 16 + r;
    float bv = bias[col];
    #pragma unroll
    for (int m = 0; m < 2; ++m) {
      #pragma unroll
      for (int j = 0; j < 4; ++j) {
        int rowj = brow + wave * 32 + m * 16 + g * 4 + j;
        out[(size_t)rowj * 1024 + col] = acc[m][n][j] + bv;
      }
    }
  }
}

// ---------------- flash attention v7 ----------------
// 2 waves x 32 q-rows = 64-row chunks -> 1024 blocks (4/CU, was 2/CU), finer
// dynamic balance, shorter drain. K/V^T staged in LDS (dbuf, XOR-swizzled),
// shared by both waves. Inner math identical to v6.
template<bool MASK>
static __device__ __forceinline__ void attn_tile_lds(
    int k0, int qw0, int lane,
    const u16* Kls, const u16* Vls,
    const bf16x8 (&qf)[2][2], f32x4 (&o)[2][4], float (&lsum)[2]) {
  const int r = lane & 15, g = lane >> 4;

  bf16x8 kf[4][2];
  #pragma unroll
  for (int kk = 0; kk < 4; ++kk) {
    int row = kk * 16 + r;
    int sw = row & 7;
    kf[kk][0] = *reinterpret_cast<const bf16x8*>(Kls + row * 64 + ((g ^ sw) * 8));
    kf[kk][1] = *reinterpret_cast<const bf16x8*>(Kls + row * 64 + (((g + 4) ^ sw) * 8));
  }
  bf16x4 vf[4][4];
  #pragma unroll
  for (int n = 0; n < 4; ++n) {
    int row = n * 16 + r;          // d-index
    int sw = row & 7;
    #pragma unroll
    for (int kk = 0; kk < 4; ++kk) {
      int blk = (g >> 1) + kk * 2; // 16B block along keys
      vf[kk][n] = *reinterpret_cast<const bf16x4*>(
          Vls + row * 64 + ((blk ^ sw) * 8) + (g & 1) * 4);
    }
  }

  #pragma unroll
  for (int h2 = 0; h2 < 2; ++h2) {
    f32x4 st[4];
    #pragma unroll
    for (int kk = 0; kk < 4; ++kk) {
      st[kk] = (f32x4){0.f, 0.f, 0.f, 0.f};
      st[kk] = __builtin_amdgcn_mfma_f32_16x16x32_bf16(kf[kk][0], qf[h2][0], st[kk], 0, 0, 0);
      st[kk] = __builtin_amdgcn_mfma_f32_16x16x32_bf16(kf[kk][1], qf[h2][1], st[kk], 0, 0, 0);
    }
    const int q = qw0 + h2 * 16 + r;
    float p[16];
    #pragma unroll
    for (int kk = 0; kk < 4; ++kk)
      #pragma unroll
      for (int j = 0; j < 4; ++j) {
        float e = exp2f(st[kk][j]);
        p[kk * 4 + j] = (!MASK || (k0 + kk * 16 + g * 4 + j <= q)) ? e : 0.f;
      }
    float rs = 0.f;
    #pragma unroll
    for (int i = 0; i < 16; ++i) rs += p[i];
    lsum[h2] += rs;                       // per-lane partial; reduced at end

    bf16x4 pf[4];
    #pragma unroll
    for (int kk = 0; kk < 4; ++kk)
      #pragma unroll
      for (int j = 0; j < 4; ++j)
        pf[kk][j] = (short)f2bf(p[kk * 4 + j]);

    #pragma unroll
    for (int n = 0; n < 4; ++n)
      #pragma unroll
      for (int kk = 0; kk < 4; ++kk)
        o[h2][n] = __builtin_amdgcn_mfma_f32_16x16x16bf16_1k(pf[kk], vf[kk][n], o[h2][n], 0, 0, 0);
  }
}

// grid: (32 chunks heavy-first, B*H), block: 128 (2 waves x 32 q-rows)
__global__ __launch_bounds__(128) void attn_kernel(
    const u16* __restrict__ Q, const u16* __restrict__ K,
    const u16* __restrict__ VT, u16* __restrict__ O) {
  __shared__ u16 Kls[2][64 * 64];   // 2 x 8KB, swizzled
  __shared__ u16 Vls[2][64 * 64];   // 2 x 8KB, swizzled

  const int tid  = threadIdx.x;
  const int lane = tid & 63;
  const int wave = tid >> 6;        // 0..1
  const int r = lane & 15, g = lane >> 4;
  const int bh = blockIdx.y;
  const int c = 31 - blockIdx.x;                 // heavy chunks first
  const int qw0 = c * 64 + wave * 32;
  const u16* Kp  = K  + (size_t)bh * 2048 * 64;
  const u16* VTp = VT + (size_t)bh * 64 * 2048;
  const u16* Qp  = Q  + (size_t)bh * 2048 * 64;

  bf16x8 qf[2][2];
  #pragma unroll
  for (int h2 = 0; h2 < 2; ++h2) {
    const u16* qp = Qp + (size_t)(qw0 + h2 * 16 + r) * 64 + g * 8;
    qf[h2][0] = *reinterpret_cast<const bf16x8*>(qp);
    qf[h2][1] = *reinterpret_cast<const bf16x8*>(qp + 32);
  }

  f32x4 o[2][4];
  #pragma unroll
  for (int h2 = 0; h2 < 2; ++h2)
    #pragma unroll
    for (int n = 0; n < 4; ++n) o[h2][n] = (f32x4){0.f, 0.f, 0.f, 0.f};
  float lsum[2] = {0.f, 0.f};

  // stage tile t: 8 K-chunks + 8 V-chunks of 1KB, 4 per wave.
  // LDS element (row, blk*8+w) holds global element (row, (blk^(row&7))*8+w).
  auto stage = [&](int t, int buf) {
    const int k0s = t * 64;
    #pragma unroll
    for (int i = 0; i < 4; ++i) {
      int chunk = wave * 4 + i;
      int row = chunk * 8 + (lane >> 3);
      int blk = lane & 7;
      int off = ((blk ^ (row & 7)) * 8);
      __builtin_amdgcn_global_load_lds(
          (const AS1 void*)(Kp + (size_t)(k0s + row) * 64 + off),
          (AS3 void*)(&Kls[buf][chunk * 512]), 16, 0, 0);
      __builtin_amdgcn_global_load_lds(
          (const AS1 void*)(VTp + (size_t)row * 2048 + k0s + off),
          (AS3 void*)(&Vls[buf][chunk * 512]), 16, 0, 0);
    }
  };

  const int nT = c + 1;            // kv tiles; last is diagonal (masked)
  stage(0, 0);
  __syncthreads();
  int cur = 0;
  for (int t = 0; t < nT; ++t) {
    if (t + 1 < nT) stage(t + 1, cur ^ 1);
    if (t < nT - 1)
      attn_tile_lds<false>(t * 64, qw0, lane, Kls[cur], Vls[cur], qf, o, lsum);
    else
      attn_tile_lds<true>(t * 64, qw0, lane, Kls[cur], Vls[cur], qf, o, lsum);
    __syncthreads();               // drains vmcnt (stage done) + reads done
    cur ^= 1;
  }

  // cross-lane reduce of per-lane lsum partials (once per kernel)
  #pragma unroll
  for (int h2 = 0; h2 < 2; ++h2) {
    lsum[h2] += __shfl_xor(lsum[h2], 16);
    lsum[h2] += __shfl_xor(lsum[h2], 32);
  }

  // epilogue: normalize, write attn_out [B][T][H*64+d]
  const int b = bh >> 4, h = bh & 15;
  #pragma unroll
  for (int h2 = 0; h2 < 2; ++h2) {
    float linv[4];
    #pragma unroll
    for (int j = 0; j < 4; ++j)
      linv[j] = 1.f / __shfl(lsum[h2], (lane & 48) | (g * 4 + j));
    #pragma unroll
    for (int n = 0; n < 4; ++n) {
      #pragma unroll
      for (int j = 0; j < 4; ++j) {
        size_t row = (size_t)b * 2048 + qw0 + h2 * 16 + g * 4 + j;
        O[row * 1024 + h * 64 + n * 16 + r] = f2bf(o[h2][n][j] * linv[j]);
      }
    }
  }
}

// ---------------- launch ----------------

extern "C" void kernel_launch(void* const* d_in, const int* in_sizes, int n_in,
                              void* d_out, int out_size, void* d_ws, size_t ws_size,
                              hipStream_t stream) {
  const float* x    = (const float*)d_in[0];
  const float* Wqkv = (const float*)d_in[1];
  const float* bqkv = (const float*)d_in[2];
  const float* Wout = (const float*)d_in[3];
  const float* bout = (const float*)d_in[4];
  float* out = (float*)d_out;

  char* p = (char*)d_ws;
  u16* xbf   = (u16*)p; p += (size_t)4096 * 1024 * 2;   // aliased by attn below
  u16* wqkvT = (u16*)p; p += (size_t)3072 * 1024 * 2;
  u16* woutT = (u16*)p; p += (size_t)1024 * 1024 * 2;
  u16* Qb    = (u16*)p; p += (size_t)32 * 2048 * 64 * 2;
  u16* Kb    = (u16*)p; p += (size_t)32 * 2048 * 64 * 2;
  u16* Vb    = (u16*)p; p += (size_t)32 * 2048 * 64 * 2;
  u16* Vt    = (u16*)p; p += (size_t)32 * 64 * 2048 * 2;
  u16* attn  = xbf;   // xbf is dead after gemm_qkv; attn written after it

  cast_x_kernel<<<4096, 256, 0, stream>>>(x, xbf, 4096 * 1024 / 4);
  transpose_cast_kernel<<<dim3(96, 32), dim3(32, 8), 0, stream>>>(Wqkv, wqkvT, 1024, 3072);
  transpose_cast_kernel<<<dim3(32, 32), dim3(32, 8), 0, stream>>>(Wout, woutT, 1024, 1024);
  gemm_qkv_kernel<<<dim3(24, 32), 256, 0, stream>>>(xbf, wqkvT, bqkv, Qb, Kb, Vb);
  transpose_v_kernel<<<dim3(32, 32), dim3(64, 8), 0, stream>>>(Vb, Vt);
  attn_kernel<<<dim3(32, 32), 128, 0, stream>>>(Qb, Kb, Vt, attn);
  gemm_out_kernel<<<dim3(16, 32), 256, 0, stream>>>(attn, woutT, bout, out);
}

// Round 12
// 244.693 us; speedup vs baseline: 1.0328x; 1.0328x over previous
//
#include <hip/hip_runtime.h>
#include <hip/hip_bf16.h>
#include <cstdint>
#include <cstddef>

typedef unsigned short u16;
typedef __attribute__((ext_vector_type(8))) short bf16x8;
typedef __attribute__((ext_vector_type(4))) short bf16x4;
typedef __attribute__((ext_vector_type(4))) float f32x4;

#define AS1 __attribute__((address_space(1)))
#define AS3 __attribute__((address_space(3)))

// round-to-nearest-even f32 -> bf16 bits (manual; prep kernels)
static __device__ __forceinline__ u16 f2bf(float f) {
  union { float f; unsigned u; } c;
  c.f = f;
  unsigned r = c.u + 0x7fffu + ((c.u >> 16) & 1u);
  return (u16)(r >> 16);
}

// f32 -> bf16 bits via HIP intrinsic (RNE); compiler can pack pairs into
// v_cvt_pk_bf16_f32 — hot-path version.
static __device__ __forceinline__ u16 f2bf_cvt(float f) {
  __hip_bfloat16 h = __float2bfloat16(f);
  return *reinterpret_cast<u16*>(&h);
}

// ---------------- prep kernels ----------------

__global__ __launch_bounds__(256) void cast_x_kernel(const float* __restrict__ in,
                                                     u16* __restrict__ out, int n4) {
  int i = blockIdx.x * blockDim.x + threadIdx.x;
  if (i < n4) {
    float4 v = reinterpret_cast<const float4*>(in)[i];
    ushort4 o;
    o.x = f2bf(v.x); o.y = f2bf(v.y); o.z = f2bf(v.z); o.w = f2bf(v.w);
    reinterpret_cast<ushort4*>(out)[i] = o;
  }
}

// out[C][R] (bf16) = transpose of in[R][C] (f32)
__global__ __launch_bounds__(256) void transpose_cast_kernel(const float* __restrict__ in,
                                                             u16* __restrict__ out,
                                                             int R, int C) {
  __shared__ float tile[32][33];
  int bx = blockIdx.x, by = blockIdx.y;
  int tx = threadIdx.x, ty = threadIdx.y;
  #pragma unroll
  for (int i = ty; i < 32; i += 8)
    tile[i][tx] = in[(size_t)(by * 32 + i) * C + bx * 32 + tx];
  __syncthreads();
  #pragma unroll
  for (int i = ty; i < 32; i += 8)
    out[(size_t)(bx * 32 + i) * R + by * 32 + tx] = f2bf(tile[tx][i]);
}

// V [BH][2048][64] bf16 -> Vt [BH][64][2048] bf16. grid (32 t-tiles, 32 bh), block (64,8)
__global__ __launch_bounds__(512) void transpose_v_kernel(const u16* __restrict__ in,
                                                          u16* __restrict__ out) {
  __shared__ u16 tile[64][65];
  const int bh = blockIdx.y;
  const int t0 = blockIdx.x * 64;
  const int tx = threadIdx.x, ty = threadIdx.y;
  const u16* src = in + (size_t)bh * 2048 * 64;
  u16* dst = out + (size_t)bh * 64 * 2048;
  #pragma unroll
  for (int i = ty; i < 64; i += 8)
    tile[i][tx] = src[(size_t)(t0 + i) * 64 + tx];     // tile[t][d]
  __syncthreads();
  #pragma unroll
  for (int i = ty; i < 64; i += 8)
    dst[(size_t)i * 2048 + t0 + tx] = tile[tx][i];
}

// ---------------- GEMM mainloop (m97 structure: 128x128 tile, BK=64) ----------------
static __device__ __forceinline__ void gemm_mainloop(
    const u16* __restrict__ A, const u16* __restrict__ Bt, int K,
    int brow, int bcol, u16* lsA, u16* lsB, f32x4 acc[4][4]) {
  const int tid  = threadIdx.x;
  const int lane = tid & 63;
  const int wave = tid >> 6;
  const int wr = wave >> 1, wc = wave & 1;
  const int r = lane & 15, g = lane >> 4;

  for (int k0 = 0; k0 < K; k0 += 64) {
    #pragma unroll
    for (int i = 0; i < 4; ++i) {
      int chunk = i * 4 + wave;          // 16 chunks x 1KB per tile
      int e = (chunk * 64 + lane) * 8;   // element index in tile
      int rr = e >> 6, cc = e & 63;
      __builtin_amdgcn_global_load_lds(
          (const AS1 void*)(A + (size_t)(brow + rr) * K + k0 + cc),
          (AS3 void*)(lsA + chunk * 512), 16, 0, 0);
      __builtin_amdgcn_global_load_lds(
          (const AS1 void*)(Bt + (size_t)(bcol + rr) * K + k0 + cc),
          (AS3 void*)(lsB + chunk * 512), 16, 0, 0);
    }
    __syncthreads();
    #pragma unroll
    for (int kk = 0; kk < 64; kk += 32) {
      bf16x8 af[4], bfr[4];
      #pragma unroll
      for (int m = 0; m < 4; ++m)
        af[m] = *reinterpret_cast<const bf16x8*>(lsA + (wr * 64 + m * 16 + r) * 64 + kk + g * 8);
      #pragma unroll
      for (int n = 0; n < 4; ++n)
        bfr[n] = *reinterpret_cast<const bf16x8*>(lsB + (wc * 64 + n * 16 + r) * 64 + kk + g * 8);
      #pragma unroll
      for (int m = 0; m < 4; ++m)
        #pragma unroll
        for (int n = 0; n < 4; ++n)
          acc[m][n] = __builtin_amdgcn_mfma_f32_16x16x32_bf16(af[m], bfr[n], acc[m][n], 0, 0, 0);
    }
    __syncthreads();
  }
}

// QKV projection; scatter Q/K/V -> [B*H][T][64] (V transposed later).
// Q gets 1/sqrt(64)*log2(e) folded (attention works in exp2 domain).
// XCD-aware block swizzle (768 blocks, 768%8==0 -> bijective).
__global__ __launch_bounds__(256) void gemm_qkv_kernel(
    const u16* __restrict__ A, const u16* __restrict__ Bt,
    const float* __restrict__ bias,
    u16* __restrict__ Qo, u16* __restrict__ Ko, u16* __restrict__ Vo) {
  __shared__ u16 lsA[128 * 64];
  __shared__ u16 lsB[128 * 64];
  f32x4 acc[4][4];
  #pragma unroll
  for (int m = 0; m < 4; ++m)
    #pragma unroll
    for (int n = 0; n < 4; ++n)
      acc[m][n] = (f32x4){0.f, 0.f, 0.f, 0.f};

  const int lin = blockIdx.y * 24 + blockIdx.x;   // dispatch order
  const int nl  = (lin & 7) * 96 + (lin >> 3);    // XCD swizzle
  const int brow = (nl / 24) * 128;
  const int bcol = (nl % 24) * 128;
  gemm_mainloop(A, Bt, 1024, brow, bcol, lsA, lsB, acc);

  const float QSC = 0.125f * 1.44269504088896f;
  const int lane = threadIdx.x & 63;
  const int wave = threadIdx.x >> 6;
  const int wr = wave >> 1, wc = wave & 1;
  const int r = lane & 15, g = lane >> 4;
  #pragma unroll
  for (int n = 0; n < 4; ++n) {
    int col = bcol + wc * 64 + n * 16 + r;         // in [0,3072)
    int s = col >> 10, h = (col >> 6) & 15, d = col & 63;
    float bv = bias[col];
    u16* dst = (s == 0) ? Qo : (s == 1) ? Ko : Vo;
    float sc = (s == 0) ? QSC : 1.f;
    #pragma unroll
    for (int m = 0; m < 4; ++m) {
      #pragma unroll
      for (int j = 0; j < 4; ++j) {
        int rowj = brow + wr * 64 + m * 16 + g * 4 + j;   // b*2048 + t
        int b = rowj >> 11, t = rowj & 2047;
        dst[((size_t)(b * 16 + h) * 2048 + t) * 64 + d] = f2bf_cvt((acc[m][n][j] + bv) * sc);
      }
    }
  }
}

// Output projection: out[4096][1024] f32 = attn @ Wout + b_out
// 128x64 tiles -> 512 blocks (2/CU). 4 waves stacked on M. XCD swizzle.
__global__ __launch_bounds__(256) void gemm_out_kernel(
    const u16* __restrict__ A, const u16* __restrict__ Bt,
    const float* __restrict__ bias, float* __restrict__ out) {
  __shared__ u16 lsA[128 * 64];   // 16KB
  __shared__ u16 lsB[64 * 64];    // 8KB
  f32x4 acc[2][4];
  #pragma unroll
  for (int m = 0; m < 2; ++m)
    #pragma unroll
    for (int n = 0; n < 4; ++n)
      acc[m][n] = (f32x4){0.f, 0.f, 0.f, 0.f};

  const int lin = blockIdx.y * 16 + blockIdx.x;
  const int nl  = (lin & 7) * 64 + (lin >> 3);    // 512 blocks, bijective
  const int brow = (nl / 16) * 128;
  const int bcol = (nl % 16) * 64;

  const int tid  = threadIdx.x;
  const int lane = tid & 63;
  const int wave = tid >> 6;
  const int r = lane & 15, g = lane >> 4;

  for (int k0 = 0; k0 < 1024; k0 += 64) {
    // stage: 16 A-chunks + 8 B-chunks of 1KB, 6 per wave (wave-uniform branch)
    #pragma unroll
    for (int i = 0; i < 6; ++i) {
      int chunk = wave * 6 + i;
      if (chunk < 16) {
        int e = (chunk * 64 + lane) * 8;
        int rr = e >> 6, cc = e & 63;
        __builtin_amdgcn_global_load_lds(
            (const AS1 void*)(A + (size_t)(brow + rr) * 1024 + k0 + cc),
            (AS3 void*)(lsA + chunk * 512), 16, 0, 0);
      } else {
        int ch = chunk - 16;
        int e = (ch * 64 + lane) * 8;
        int rr = e >> 6, cc = e & 63;
        __builtin_amdgcn_global_load_lds(
            (const AS1 void*)(Bt + (size_t)(bcol + rr) * 1024 + k0 + cc),
            (AS3 void*)(lsB + ch * 512), 16, 0, 0);
      }
    }
    __syncthreads();
    #pragma unroll
    for (int kk = 0; kk < 64; kk += 32) {
      bf16x8 af[2], bfr[4];
      #pragma unroll
      for (int m = 0; m < 2; ++m)
        af[m] = *reinterpret_cast<const bf16x8*>(lsA + (wave * 32 + m * 16 + r) * 64 + kk + g * 8);
      #pragma unroll
      for (int n = 0; n < 4; ++n)
        bfr[n] = *reinterpret_cast<const bf16x8*>(lsB + (n * 16 + r) * 64 + kk + g * 8);
      #pragma unroll
      for (int m = 0; m < 2; ++m)
        #pragma unroll
        for (int n = 0; n < 4; ++n)
          acc[m][n] = __builtin_amdgcn_mfma_f32_16x16x32_bf16(af[m], bfr[n], acc[m][n], 0, 0, 0);
    }
    __syncthreads();
  }

  #pragma unroll
  for (int n = 0; n < 4; ++n) {
    int col = bcol + n * 16 + r;
    float bv = bias[col];
    #pragma unroll
    for (int m = 0; m < 2; ++m) {
      #pragma unroll
      for (int j = 0; j < 4; ++j) {
        int rowj = brow + wave * 32 + m * 16 + g * 4 + j;
        out[(size_t)rowj * 1024 + col] = acc[m][n][j] + bv;
      }
    }
  }
}

// ---------------- flash attention v6b ----------------
// Round-9 v6 structure (proven 84.6us): 4 waves x 32 q-rows = 128-row blocks,
// K/V^T staged in LDS (dbuf, XOR-swizzled both sides), shared by 4 waves.
// Change vs v6: P-pack and epilogue use hardware bf16 cvt (compiler packs
// pairs into v_cvt_pk_bf16_f32) instead of the 3-op manual RNE trick.
template<bool MASK>
static __device__ __forceinline__ void attn_tile_lds(
    int k0, int qw0, int lane,
    const u16* Kls, const u16* Vls,
    const bf16x8 (&qf)[2][2], f32x4 (&o)[2][4], float (&lsum)[2]) {
  const int r = lane & 15, g = lane >> 4;

  bf16x8 kf[4][2];
  #pragma unroll
  for (int kk = 0; kk < 4; ++kk) {
    int row = kk * 16 + r;
    int sw = row & 7;
    kf[kk][0] = *reinterpret_cast<const bf16x8*>(Kls + row * 64 + ((g ^ sw) * 8));
    kf[kk][1] = *reinterpret_cast<const bf16x8*>(Kls + row * 64 + (((g + 4) ^ sw) * 8));
  }
  bf16x4 vf[4][4];
  #pragma unroll
  for (int n = 0; n < 4; ++n) {
    int row = n * 16 + r;          // d-index
    int sw = row & 7;
    #pragma unroll
    for (int kk = 0; kk < 4; ++kk) {
      int blk = (g >> 1) + kk * 2; // 16B block along keys
      vf[kk][n] = *reinterpret_cast<const bf16x4*>(
          Vls + row * 64 + ((blk ^ sw) * 8) + (g & 1) * 4);
    }
  }

  #pragma unroll
  for (int h2 = 0; h2 < 2; ++h2) {
    f32x4 st[4];
    #pragma unroll
    for (int kk = 0; kk < 4; ++kk) {
      st[kk] = (f32x4){0.f, 0.f, 0.f, 0.f};
      st[kk] = __builtin_amdgcn_mfma_f32_16x16x32_bf16(kf[kk][0], qf[h2][0], st[kk], 0, 0, 0);
      st[kk] = __builtin_amdgcn_mfma_f32_16x16x32_bf16(kf[kk][1], qf[h2][1], st[kk], 0, 0, 0);
    }
    const int q = qw0 + h2 * 16 + r;
    float p[16];
    #pragma unroll
    for (int kk = 0; kk < 4; ++kk)
      #pragma unroll
      for (int j = 0; j < 4; ++j) {
        float e = exp2f(st[kk][j]);
        p[kk * 4 + j] = (!MASK || (k0 + kk * 16 + g * 4 + j <= q)) ? e : 0.f;
      }
    float rs = 0.f;
    #pragma unroll
    for (int i = 0; i < 16; ++i) rs += p[i];
    lsum[h2] += rs;                       // per-lane partial; reduced at end

    bf16x4 pf[4];
    #pragma unroll
    for (int kk = 0; kk < 4; ++kk)
      #pragma unroll
      for (int j = 0; j < 4; ++j)
        pf[kk][j] = (short)f2bf_cvt(p[kk * 4 + j]);

    #pragma unroll
    for (int n = 0; n < 4; ++n)
      #pragma unroll
      for (int kk = 0; kk < 4; ++kk)
        o[h2][n] = __builtin_amdgcn_mfma_f32_16x16x16bf16_1k(pf[kk], vf[kk][n], o[h2][n], 0, 0, 0);
  }
}

// grid: (16 chunks heavy-first, B*H), block: 256 (4 waves x 32 q-rows)
__global__ __launch_bounds__(256) void attn_kernel(
    const u16* __restrict__ Q, const u16* __restrict__ K,
    const u16* __restrict__ VT, u16* __restrict__ O) {
  __shared__ u16 Kls[2][64 * 64];   // 2 x 8KB, swizzled
  __shared__ u16 Vls[2][64 * 64];   // 2 x 8KB, swizzled

  const int tid  = threadIdx.x;
  const int lane = tid & 63;
  const int wave = tid >> 6;
  const int r = lane & 15, g = lane >> 4;
  const int bh = blockIdx.y;
  const int c = 15 - blockIdx.x;                 // heavy chunks first
  const int qw0 = c * 128 + wave * 32;
  const u16* Kp  = K  + (size_t)bh * 2048 * 64;
  const u16* VTp = VT + (size_t)bh * 64 * 2048;
  const u16* Qp  = Q  + (size_t)bh * 2048 * 64;

  bf16x8 qf[2][2];
  #pragma unroll
  for (int h2 = 0; h2 < 2; ++h2) {
    const u16* qp = Qp + (size_t)(qw0 + h2 * 16 + r) * 64 + g * 8;
    qf[h2][0] = *reinterpret_cast<const bf16x8*>(qp);
    qf[h2][1] = *reinterpret_cast<const bf16x8*>(qp + 32);
  }

  f32x4 o[2][4];
  #pragma unroll
  for (int h2 = 0; h2 < 2; ++h2)
    #pragma unroll
    for (int n = 0; n < 4; ++n) o[h2][n] = (f32x4){0.f, 0.f, 0.f, 0.f};
  float lsum[2] = {0.f, 0.f};

  // stage tile t into buffer buf: 8 K-chunks + 8 V-chunks of 1KB, 2 per wave.
  // LDS element (row, blk*8+w) holds global element (row, (blk^(row&7))*8+w).
  auto stage = [&](int t, int buf) {
    const int k0s = t * 64;
    #pragma unroll
    for (int i = 0; i < 2; ++i) {
      int chunk = wave * 2 + i;
      int row = chunk * 8 + (lane >> 3);
      int blk = lane & 7;
      int off = ((blk ^ (row & 7)) * 8);
      __builtin_amdgcn_global_load_lds(
          (const AS1 void*)(Kp + (size_t)(k0s + row) * 64 + off),
          (AS3 void*)(&Kls[buf][chunk * 512]), 16, 0, 0);
      __builtin_amdgcn_global_load_lds(
          (const AS1 void*)(VTp + (size_t)row * 2048 + k0s + off),
          (AS3 void*)(&Vls[buf][chunk * 512]), 16, 0, 0);
    }
  };

  const int nT = 2 * c + 2;        // kv tiles; last two are diagonal (masked)
  stage(0, 0);
  __syncthreads();
  int cur = 0;
  for (int t = 0; t < nT; ++t) {
    if (t + 1 < nT) stage(t + 1, cur ^ 1);
    if (t < nT - 2)
      attn_tile_lds<false>(t * 64, qw0, lane, Kls[cur], Vls[cur], qf, o, lsum);
    else
      attn_tile_lds<true>(t * 64, qw0, lane, Kls[cur], Vls[cur], qf, o, lsum);
    __syncthreads();               // drains vmcnt (stage done) + reads done
    cur ^= 1;
  }

  // cross-lane reduce of per-lane lsum partials (once per kernel)
  #pragma unroll
  for (int h2 = 0; h2 < 2; ++h2) {
    lsum[h2] += __shfl_xor(lsum[h2], 16);
    lsum[h2] += __shfl_xor(lsum[h2], 32);
  }

  // epilogue: normalize, write attn_out [B][T][H*64+d] (per-wave, no combine)
  const int b = bh >> 4, h = bh & 15;
  #pragma unroll
  for (int h2 = 0; h2 < 2; ++h2) {
    float linv[4];
    #pragma unroll
    for (int j = 0; j < 4; ++j)
      linv[j] = 1.f / __shfl(lsum[h2], (lane & 48) | (g * 4 + j));
    #pragma unroll
    for (int n = 0; n < 4; ++n) {
      #pragma unroll
      for (int j = 0; j < 4; ++j) {
        size_t row = (size_t)b * 2048 + qw0 + h2 * 16 + g * 4 + j;
        O[row * 1024 + h * 64 + n * 16 + r] = f2bf_cvt(o[h2][n][j] * linv[j]);
      }
    }
  }
}

// ---------------- launch ----------------

extern "C" void kernel_launch(void* const* d_in, const int* in_sizes, int n_in,
                              void* d_out, int out_size, void* d_ws, size_t ws_size,
                              hipStream_t stream) {
  const float* x    = (const float*)d_in[0];
  const float* Wqkv = (const float*)d_in[1];
  const float* bqkv = (const float*)d_in[2];
  const float* Wout = (const float*)d_in[3];
  const float* bout = (const float*)d_in[4];
  float* out = (float*)d_out;

  char* p = (char*)d_ws;
  u16* xbf   = (u16*)p; p += (size_t)4096 * 1024 * 2;   // aliased by attn below
  u16* wqkvT = (u16*)p; p += (size_t)3072 * 1024 * 2;
  u16* woutT = (u16*)p; p += (size_t)1024 * 1024 * 2;
  u16* Qb    = (u16*)p; p += (size_t)32 * 2048 * 64 * 2;
  u16* Kb    = (u16*)p; p += (size_t)32 * 2048 * 64 * 2;
  u16* Vb    = (u16*)p; p += (size_t)32 * 2048 * 64 * 2;
  u16* Vt    = (u16*)p; p += (size_t)32 * 64 * 2048 * 2;
  u16* attn  = xbf;   // xbf is dead after gemm_qkv; attn written after it

  cast_x_kernel<<<4096, 256, 0, stream>>>(x, xbf, 4096 * 1024 / 4);
  transpose_cast_kernel<<<dim3(96, 32), dim3(32, 8), 0, stream>>>(Wqkv, wqkvT, 1024, 3072);
  transpose_cast_kernel<<<dim3(32, 32), dim3(32, 8), 0, stream>>>(Wout, woutT, 1024, 1024);
  gemm_qkv_kernel<<<dim3(24, 32), 256, 0, stream>>>(xbf, wqkvT, bqkv, Qb, Kb, Vb);
  transpose_v_kernel<<<dim3(32, 32), dim3(64, 8), 0, stream>>>(Vb, Vt);
  attn_kernel<<<dim3(16, 32), 256, 0, stream>>>(Qb, Kb, Vt, attn);
  gemm_out_kernel<<<dim3(16, 32), 256, 0, stream>>>(attn, woutT, bout, out);
}